// Round 11
// baseline (1477.345 us; speedup 1.0000x reference)
//
#include <hip/hip_runtime.h>
#include <math.h>

#define TS 2048
#define XROW 72      // padded f16 row stride for x tiles (144B, 16B-aligned)
#define XT1F 4608    // f16 idx of x tile 1 (tile 0 at 0)
#define H16FLOAT 4608 // float idx of h-f16 region
#define H1F  4736    // float idx: h1 f32 [2 parity][64] (attn pooling)
#define SCRO 4864    // float idx: epilogue scratch (96)
#define SPA  4960    // float idx: attn score partials [2 parity][2]
#define LDSF 4964

typedef float f32x2 __attribute__((ext_vector_type(2)));
typedef _Float16 f16;
typedef _Float16 f16x2 __attribute__((ext_vector_type(2)));
typedef _Float16 f16x8 __attribute__((ext_vector_type(8)));

// Raw barrier: LDS-ordering only, NO vmcnt drain (stage prefetch stays in flight)
#define BAR() do { asm volatile("s_waitcnt lgkmcnt(0)" ::: "memory"); __builtin_amdgcn_s_barrier(); } while(0)

union H8 { f16x8 v8; f16x2 v2[4]; };

__device__ __forceinline__ float sigmoidf_(float v){ return __builtin_amdgcn_rcpf(1.0f+__expf(-v)); }
__device__ __forceinline__ float tanhf_(float v){
  v = fminf(15.0f, fmaxf(-15.0f, v));
  const float e = __expf(2.0f*v);
  return (e-1.0f)*__builtin_amdgcn_rcpf(e+1.0f);
}
__device__ __forceinline__ float qadd2(float v){
  float a = v + __int_as_float(__builtin_amdgcn_update_dpp(0, __float_as_int(v), 0xB1, 0xF, 0xF, true));
  return a + __int_as_float(__builtin_amdgcn_update_dpp(0, __float_as_int(a), 0x4E, 0xF, 0xF, true));
}
__device__ __forceinline__ float wsum64(float v){
  v += __int_as_float(__builtin_amdgcn_update_dpp(0, __float_as_int(v), 0x111, 0xF, 0xF, true));
  v += __int_as_float(__builtin_amdgcn_update_dpp(0, __float_as_int(v), 0x112, 0xF, 0xF, true));
  v += __int_as_float(__builtin_amdgcn_update_dpp(0, __float_as_int(v), 0x114, 0xF, 0xF, true));
  v += __int_as_float(__builtin_amdgcn_update_dpp(0, __float_as_int(v), 0x118, 0xF, 0xF, true));
  v += __int_as_float(__builtin_amdgcn_update_dpp(0, __float_as_int(v), 0x142, 0xA, 0xF, true));
  v += __int_as_float(__builtin_amdgcn_update_dpp(0, __float_as_int(v), 0x143, 0xC, 0xF, true));
  return __int_as_float(__builtin_amdgcn_readlane(__float_as_int(v), 63));
}
__device__ __forceinline__ float fdot2_(f16x2 a, f16x2 b, float c){
  return __builtin_amdgcn_fdot2(a, b, c, false);
}
// triple 16-f16 dot on preloaded inputs (24 v_dot2_f32_f16)
__device__ __forceinline__ void dot3r(const H8& u0, const H8& u1, const f16x2* w0,
                                      const f16x2* w1, const f16x2* w2,
                                      float& r0, float& r1, float& r2){
  #pragma unroll
  for (int i=0;i<4;i++){ r0=fdot2_(w0[i],u0.v2[i],r0); r1=fdot2_(w1[i],u0.v2[i],r1); r2=fdot2_(w2[i],u0.v2[i],r2); }
  #pragma unroll
  for (int i=0;i<4;i++){ r0=fdot2_(w0[4+i],u1.v2[i],r0); r1=fdot2_(w1[4+i],u1.v2[i],r1); r2=fdot2_(w2[4+i],u1.v2[i],r2); }
}

// 4 waves = 256 threads, one per SIMD:
//   wid 0: L0 half0 (+ online-softmax pooling)   wid 1: L0 half1
//   wid 2: L1 half0 + attn o in {0-15,16-31}     wid 3: L1 half1 + attn o in {32-47,48-63}
// Gate thread: rows {row0,row0+32}, quarter cols; 96 f16x2 weights; register h master.
// Attn quarter-dots reuse the L1 hh-dot input registers (zero extra LDS reads).
// Stage split across all 4 waves. Skew: L0@it, L1@it-2, attn dots@it(h1 of it-1),
// score finalized via LDS partials, pooling consumes at it+1. 1 raw barrier/step.
__global__ __launch_bounds__(256, 1)
void gru_attn_fused(const float* __restrict__ x,
                    const float* __restrict__ w_ih0, const float* __restrict__ w_hh0,
                    const float* __restrict__ b_ih0, const float* __restrict__ b_hh0,
                    const float* __restrict__ w_ih1, const float* __restrict__ w_hh1,
                    const float* __restrict__ b_ih1, const float* __restrict__ b_hh1,
                    const float* __restrict__ attn_w1, const float* __restrict__ attn_b1,
                    const float* __restrict__ attn_w2, const float* __restrict__ attn_b2,
                    const float* __restrict__ ln_g, const float* __restrict__ ln_b,
                    const float* __restrict__ head_w1, const float* __restrict__ head_b1,
                    const float* __restrict__ head_w2, const float* __restrict__ head_b2,
                    float* __restrict__ out)
{
  __shared__ float lds[LDSF];
  f16* ldsxh  = (f16*)&lds[0];          // x tiles (f16, XROW stride)
  f16* lds16h = (f16*)&lds[H16FLOAT];   // h f16 [layer][parity][64]
  const int tid  = threadIdx.x;
  const int b    = blockIdx.x;
  const int wid  = tid >> 6;
  const int lane = tid & 63;
  const float* xb = x + (size_t)b * 64 * TS;

  const int  l     = wid >> 1;                        // layer
  const int  half  = wid & 1;
  const int  row0  = (half << 4) + (lane >> 2);       // rows {row0, row0+32}
  const int  row1  = row0 + 32;
  const int  q16   = (lane & 3) << 4;                 // quarter col offset
  const int  lbase = l << 7;                          // h f16 base

  f16x2 Wih[48], Whh[48], WA[16];
  float4 SP[4];                                       // stage pipeline (4 rows-of-4)
  float bR0=0,bZ0=0,bI0=0,bH0=0,bR1=0,bZ1=0,bI1=0,bH1=0;
  float b1o1=0,b1o2=0,w2o1=0,w2o2=0,b2v=0;

  {
    const float* bih = l ? w_ih1 : w_ih0;
    const float* bhh = l ? w_hh1 : w_hh0;
    for (int r2=0;r2<2;r2++){
      const int row = r2 ? row1 : row0;
      for (int g=0; g<3; g++){
        for (int i=0;i<8;i++){
          const f32x2 vi = *(const f32x2*)(bih + (g*64+row)*64 + q16 + 2*i);
          const f32x2 vh = *(const f32x2*)(bhh + (g*64+row)*64 + q16 + 2*i);
          Wih[r2*24+g*8+i] = (f16x2){(f16)vi.x, (f16)vi.y};
          Whh[r2*24+g*8+i] = (f16x2){(f16)vh.x, (f16)vh.y};
        }
      }
    }
    for (int k=0;k<48;k++) asm volatile("" : "+v"(Wih[k]));
    for (int k=0;k<48;k++) asm volatile("" : "+v"(Whh[k]));
    const float* bi = l ? b_ih1 : b_ih0;
    const float* bh = l ? b_hh1 : b_hh0;
    bR0 = bi[row0] + bh[row0];       bR1 = bi[row1] + bh[row1];
    bZ0 = bi[64+row0] + bh[64+row0]; bZ1 = bi[64+row1] + bh[64+row1];
    bI0 = bi[128+row0];              bI1 = bi[128+row1];
    bH0 = bh[128+row0];              bH1 = bh[128+row1];
  }
  if (l == 1) {
    const int o1 = (half << 5) + (lane >> 2);
    const int o2 = o1 + 16;
    for (int i=0;i<8;i++){
      const f32x2 v1 = *(const f32x2*)(attn_w1 + o1*64 + q16 + 2*i);
      const f32x2 v2 = *(const f32x2*)(attn_w1 + o2*64 + q16 + 2*i);
      WA[i]   = (f16x2){(f16)v1.x, (f16)v1.y};
      WA[8+i] = (f16x2){(f16)v2.x, (f16)v2.y};
    }
    for (int k=0;k<16;k++) asm volatile("" : "+v"(WA[k]));
    b1o1 = attn_b1[o1]; b1o2 = attn_b1[o2];
    w2o1 = attn_w2[o1]; w2o2 = attn_w2[o2];
  }
  b2v = attn_b2[0];

  // prologue: zero h f16 + h1 f32 + score partials, stage x tile 0 (f16 transpose)
  if (tid < 128) ((uint32_t*)lds16h)[tid] = 0u;
  if (tid < 128) lds[H1F + tid] = 0.f;
  if (tid < 4)   lds[SPA + tid] = 0.f;
  {
    const int c = tid >> 2, t0 = (tid & 3) << 4;
    #pragma unroll
    for (int m4=0;m4<4;m4++){
      float4 v = *(const float4*)(xb + c*TS + t0 + 4*m4);
      ldsxh[(t0+4*m4+0)*XROW + c] = (f16)v.x;
      ldsxh[(t0+4*m4+1)*XROW + c] = (f16)v.y;
      ldsxh[(t0+4*m4+2)*XROW + c] = (f16)v.z;
      ldsxh[(t0+4*m4+3)*XROW + c] = (f16)v.w;
    }
  }
  __syncthreads();

  float st0R=0,st0Z=0,st0N=0, st1R=0,st1Z=0,st1N=0;  // ih-dot stash
  float hold0=0.f, hold1=0.f;                         // register h master
  float am=-1e30f, aZ=0.f, aP=0.f;                    // pooling (wid 0)
  float hA=0.f, hB=0.f;                               // h1 parity stash (wid 0)

  // preloop: L0 ih stash for t=0
  if (l == 0) {
    const f16* xv = ldsxh + q16;
    H8 s0,s1; s0.v8 = *(const f16x8*)xv; s1.v8 = *(const f16x8*)(xv+8);
    float a0=0,a1=0,a2=0;
    dot3r(s0,s1, Wih+0,  Wih+8,  Wih+16, a0,a1,a2); st0R=a0; st0Z=a1; st0N=a2;
    a0=0;a1=0;a2=0;
    dot3r(s0,s1, Wih+24, Wih+32, Wih+40, a0,a1,a2); st1R=a0; st1Z=a1; st1N=a2;
  }

  auto step = [&](const int it_, const int RB) {
    const int tile_ = it_ >> 6;
    const int xsel_ = tile_ & 1;
    const int tt_   = it_ & 63;

    // ---- pooling (wid 0): consume s(t) from prev iter, prefetch h1 f32 ----
    if (wid == 0) {
      if (it_ >= 4 && it_ <= TS+3) {
        const f32x2 sp2 = *(const f32x2*)&lds[SPA + ((RB^1)<<1)];
        const float s  = sp2.x + sp2.y + b2v;
        const float hp = RB ? hA : hB;
        const float mn = fmaxf(am, s);
        const float sc = __expf(am - mn);
        const float p  = __expf(s - mn);
        aZ = aZ*sc + p;
        aP = aP*sc + p*hp;
        am = mn;
      }
      if (it_ >= 3 && it_ <= TS+2) {
        const float hv = lds[H1F + (RB<<6) + lane];
        if (RB == 0) hA = hv; else hB = hv;
      }
    }

    // ---- stage (all 4 waves; 16 rows each) ----
    if (tile_ <= 30) {
      if (tt_ == 0) {
        const float* src = xb + (size_t)((wid<<4) + (lane>>4))*TS + (tile_+1)*64 + ((lane&15)<<2);
        SP[0] = *(const float4*)(src);
        SP[1] = *(const float4*)(src + 4*TS);
        SP[2] = *(const float4*)(src + 8*TS);
        SP[3] = *(const float4*)(src + 12*TS);
      } else if (tt_ == 32) {
        f16* dsth = ldsxh + (xsel_ ? 0 : XT1F);
        const int c0 = lane >> 4, t4 = (lane & 15) << 2;
        #pragma unroll
        for (int k=0;k<4;k++){
          const int cc = (wid<<4) + (k<<2) + c0;
          dsth[(t4+0)*XROW + cc] = (f16)SP[k].x;
          dsth[(t4+1)*XROW + cc] = (f16)SP[k].y;
          dsth[(t4+2)*XROW + cc] = (f16)SP[k].z;
          dsth[(t4+3)*XROW + cc] = (f16)SP[k].w;
        }
      }
    }

    // ---- gates + folded attn ----
    const bool act     = (l==0) ? (it_ < TS) : (it_ >= 2 && it_ <= TS+1);
    const bool attnAct = (l==1) && (it_ >= 3 && it_ <= TS+2);
    H8 u0, u1;
    if (act | attnAct) {
      const f16* hv = lds16h + lbase + (RB<<6) + q16;
      u0.v8 = *(const f16x8*)hv;
      u1.v8 = *(const f16x8*)(hv+8);
    }
    if (act) {
      float cr0=0,cz0=0,cn0=0, cr1=0,cz1=0,cn1=0;
      dot3r(u0,u1, Whh+0,  Whh+8,  Whh+16, cr0,cz0,cn0);
      dot3r(u0,u1, Whh+24, Whh+32, Whh+40, cr1,cz1,cn1);
      const float sr0=qadd2(st0R+cr0), sz0=qadd2(st0Z+cz0), xn0=qadd2(st0N), hn0=qadd2(cn0);
      const float sr1=qadd2(st1R+cr1), sz1=qadd2(st1Z+cz1), xn1=qadd2(st1N), hn1=qadd2(cn1);
      const float r0=sigmoidf_(sr0+bR0), z0=sigmoidf_(sz0+bZ0);
      const float n0=tanhf_((xn0+bI0) + r0*(hn0+bH0));
      const float r1=sigmoidf_(sr1+bR1), z1=sigmoidf_(sz1+bZ1);
      const float n1=tanhf_((xn1+bI1) + r1*(hn1+bH1));
      hold0 = n0 + z0*(hold0 - n0);   // exact in all quad lanes
      hold1 = n1 + z1*(hold1 - n1);
      if ((lane & 3) == 0) {
        lds16h[lbase + ((RB^1)<<6) + row0] = (f16)hold0;
        lds16h[lbase + ((RB^1)<<6) + row1] = (f16)hold1;
        if (l == 1) {
          lds[H1F + ((RB^1)<<6) + row0] = hold0;
          lds[H1F + ((RB^1)<<6) + row1] = hold1;
        }
      }
    }
    if (attnAct) {
      float d1=0.f, d2=0.f;
      #pragma unroll
      for (int i=0;i<4;i++){ d1=fdot2_(WA[i],  u0.v2[i],d1); d2=fdot2_(WA[8+i], u0.v2[i],d2); }
      #pragma unroll
      for (int i=0;i<4;i++){ d1=fdot2_(WA[4+i],u1.v2[i],d1); d2=fdot2_(WA[12+i],u1.v2[i],d2); }
      const float a1 = tanhf_(qadd2(d1) + b1o1);
      const float a2 = tanhf_(qadd2(d2) + b1o2);
      const float c  = w2o1*a1 + w2o2*a2;
      const float v  = ((lane & 3) == 0) ? c : 0.f;
      const float part = wsum64(v);
      if (lane == 0) lds[SPA + (RB<<1) + half] = part;
    }
    // ---- ih stash for next iteration ----
    if (l == 0) {
      const int ix = it_ + 1;
      if (ix < TS) {
        const f16* xv = ldsxh + (((ix>>6)&1) ? XT1F : 0) + (ix&63)*XROW + q16;
        H8 s0,s1; s0.v8 = *(const f16x8*)xv; s1.v8 = *(const f16x8*)(xv+8);
        float a0=0,a1=0,a2=0;
        dot3r(s0,s1, Wih+0,  Wih+8,  Wih+16, a0,a1,a2); st0R=a0; st0Z=a1; st0N=a2;
        a0=0;a1=0;a2=0;
        dot3r(s0,s1, Wih+24, Wih+32, Wih+40, a0,a1,a2); st1R=a0; st1Z=a1; st1N=a2;
      }
    } else {
      if (it_ >= 1 && it_ <= TS) {
        const f16* gv = lds16h + (RB<<6) + q16;   // h0[RB]
        H8 s0,s1; s0.v8 = *(const f16x8*)gv; s1.v8 = *(const f16x8*)(gv+8);
        float a0=0,a1=0,a2=0;
        dot3r(s0,s1, Wih+0,  Wih+8,  Wih+16, a0,a1,a2); st0R=a0; st0Z=a1; st0N=a2;
        a0=0;a1=0;a2=0;
        dot3r(s0,s1, Wih+24, Wih+32, Wih+40, a0,a1,a2); st1R=a0; st1Z=a1; st1N=a2;
      }
    }
    BAR();
  };

  #pragma unroll 1
  for (int itb = 0; itb < TS + 4; itb += 2) {
    step(itb,   0);
    step(itb+1, 1);
  }

  // ---------------- epilogue ----------------
  if (wid == 0) {
    const float pooled = aP / aZ;
    float mu = pooled;
    #pragma unroll
    for (int m=1;m<64;m<<=1) mu += __shfl_xor(mu, m, 64);
    mu *= (1.0f/64.0f);
    const float d = pooled - mu;
    float var = d*d;
    #pragma unroll
    for (int m=1;m<64;m<<=1) var += __shfl_xor(var, m, 64);
    var *= (1.0f/64.0f);
    const float y = d * rsqrtf(var + 1e-5f) * ln_g[lane] + ln_b[lane];
    lds[SCRO + lane] = y;
  }
  __syncthreads();
  if (tid < 32) {
    const float* hw = head_w1 + tid*64;
    float acc = head_b1[tid];
    #pragma unroll
    for (int k=0;k<16;k++){
      const float4 w4 = ((const float4*)hw)[k];
      acc += w4.x*lds[SCRO+4*k+0] + w4.y*lds[SCRO+4*k+1]
           + w4.z*lds[SCRO+4*k+2] + w4.w*lds[SCRO+4*k+3];
    }
    const float u = 0.5f*acc*(1.0f + erff(acc*0.70710678118654752f)); // exact GELU
    lds[SCRO + 64 + tid] = u;
  }
  __syncthreads();
  if (tid < 8) {
    const float* hw = head_w2 + tid*32;
    float acc = head_b2[tid];
    #pragma unroll
    for (int k=0;k<8;k++){
      const float4 w4 = ((const float4*)hw)[k];
      acc += w4.x*lds[SCRO+64+4*k+0] + w4.y*lds[SCRO+64+4*k+1]
           + w4.z*lds[SCRO+64+4*k+2] + w4.w*lds[SCRO+64+4*k+3];
    }
    out[b*8 + tid] = acc;
  }
}

extern "C" void kernel_launch(void* const* d_in, const int* in_sizes, int n_in,
                              void* d_out, int out_size, void* d_ws, size_t ws_size,
                              hipStream_t stream) {
  (void)in_sizes; (void)n_in; (void)d_ws; (void)ws_size; (void)out_size;
  const float* x       = (const float*)d_in[0];
  const float* w_ih0   = (const float*)d_in[1];
  const float* w_hh0   = (const float*)d_in[2];
  const float* b_ih0   = (const float*)d_in[3];
  const float* b_hh0   = (const float*)d_in[4];
  const float* w_ih1   = (const float*)d_in[5];
  const float* w_hh1   = (const float*)d_in[6];
  const float* b_ih1   = (const float*)d_in[7];
  const float* b_hh1   = (const float*)d_in[8];
  const float* attn_w1 = (const float*)d_in[9];
  const float* attn_b1 = (const float*)d_in[10];
  const float* attn_w2 = (const float*)d_in[11];
  const float* attn_b2 = (const float*)d_in[12];
  const float* ln_g    = (const float*)d_in[13];
  const float* ln_b    = (const float*)d_in[14];
  const float* head_w1 = (const float*)d_in[15];
  const float* head_b1 = (const float*)d_in[16];
  const float* head_w2 = (const float*)d_in[17];
  const float* head_b2 = (const float*)d_in[18];
  hipLaunchKernelGGL(gru_attn_fused, dim3(256), dim3(256), 0, stream,
                     x, w_ih0, w_hh0, b_ih0, b_hh0, w_ih1, w_hh1, b_ih1, b_hh1,
                     attn_w1, attn_b1, attn_w2, attn_b2, ln_g, ln_b,
                     head_w1, head_b1, head_w2, head_b2, (float*)d_out);
}

// Round 12
// 792.345 us; speedup vs baseline: 1.8645x; 1.8645x over previous
//
#include <hip/hip_runtime.h>
#include <math.h>

#define TS 2048

typedef float f32x2 __attribute__((ext_vector_type(2)));
typedef _Float16 f16;
typedef _Float16 f16x2 __attribute__((ext_vector_type(2)));
typedef _Float16 f16x8 __attribute__((ext_vector_type(8)));

// LDS float-index map (13920 f32 = 55.7 KB)
//  ldsx : f16 [2][64][80]  x tiles (rows 160B, stage writes lane=c contiguous)
//  xg0/xg1 : f32 [16][192] precomputed W_ih·input + b_ih rings
//  h0h : f16 [32][64] h0 ring (32-deep: feeder reads t-1 across SB boundary)
//  h1h : f16 [16][64] h1 ring ; h1f : f32 [16][64] (pooling)
#define XG0_B  5120
#define XG1_B  8192
#define H0H_B  11264
#define H1H_B  12288
#define H1F_B  12800
#define SCRO_B 13824
#define LDSF   13920

// Block barrier: LDS-order only, no vmcnt drain (stage prefetch stays in flight)
#define BAR() do { asm volatile("s_waitcnt lgkmcnt(0)" ::: "memory"); __builtin_amdgcn_s_barrier(); } while(0)
// Intra-wave fence: recurrence waves' write(t-1) -> read(t) (lockstep wave, no barrier)
#define FEN() asm volatile("s_waitcnt lgkmcnt(0)" ::: "memory")

union H8 { f16x8 v8; f16x2 v2[4]; };

__device__ __forceinline__ float sigmoidf_(float v){ return __builtin_amdgcn_rcpf(1.0f+__expf(-v)); }
__device__ __forceinline__ float tanhf_(float v){
  v = fminf(15.0f, fmaxf(-15.0f, v));
  const float e = __expf(2.0f*v);
  return (e-1.0f)*__builtin_amdgcn_rcpf(e+1.0f);
}
// pair (xor1) sum via DPP quad_perm [1,0,3,2]
__device__ __forceinline__ float qadd1(float v){
  return v + __int_as_float(__builtin_amdgcn_update_dpp(0, __float_as_int(v), 0xB1, 0xF, 0xF, true));
}
__device__ __forceinline__ float wsum64(float v){
  v += __int_as_float(__builtin_amdgcn_update_dpp(0, __float_as_int(v), 0x111, 0xF, 0xF, true));
  v += __int_as_float(__builtin_amdgcn_update_dpp(0, __float_as_int(v), 0x112, 0xF, 0xF, true));
  v += __int_as_float(__builtin_amdgcn_update_dpp(0, __float_as_int(v), 0x114, 0xF, 0xF, true));
  v += __int_as_float(__builtin_amdgcn_update_dpp(0, __float_as_int(v), 0x118, 0xF, 0xF, true));
  v += __int_as_float(__builtin_amdgcn_update_dpp(0, __float_as_int(v), 0x142, 0xA, 0xF, true));
  v += __int_as_float(__builtin_amdgcn_update_dpp(0, __float_as_int(v), 0x143, 0xC, 0xF, true));
  return __int_as_float(__builtin_amdgcn_readlane(__float_as_int(v), 63));
}
__device__ __forceinline__ float fdot2_(f16x2 a, f16x2 b, float c){
  return __builtin_amdgcn_fdot2(a, b, c, false);
}
// 6 half-dots (rows {i2,i2+32} x 3 gates, 32-f16 half each): 96 fdot2
__device__ __forceinline__ void dot6(const f16* vec, const f16x2* Wp,
                                     float& a00, float& a01, float& a02,
                                     float& a10, float& a11, float& a12){
  H8 u[4];
  u[0].v8 = *(const f16x8*)(vec);
  u[1].v8 = *(const f16x8*)(vec+8);
  u[2].v8 = *(const f16x8*)(vec+16);
  u[3].v8 = *(const f16x8*)(vec+24);
  #pragma unroll
  for (int m=0;m<16;m++){
    const f16x2 hm = u[m>>2].v2[m&3];
    a00 = fdot2_(Wp[m],    hm, a00);
    a01 = fdot2_(Wp[16+m], hm, a01);
    a02 = fdot2_(Wp[32+m], hm, a02);
    a10 = fdot2_(Wp[48+m], hm, a10);
    a11 = fdot2_(Wp[64+m], hm, a11);
    a12 = fdot2_(Wp[80+m], hm, a12);
  }
}

// 7 waves = 448 threads (wid%4 = SIMD):
//  w0 = L0 recurrence   w1 = L1 recurrence   (critical chains, setprio 1)
//  w2 = F1: xg1 = W_ih1·h0 + b_ih1 (1 SB behind L0)
//  w3 = F0: xg0 = W_ih0·x  + b_ih0 (1 SB ahead of L0)
//  w4 = x stager        w5 = idle (keeps L1's SIMD clean)   w6 = attn+pool
// Superblocks of D=8 steps; ONE block barrier per superblock.
__global__ __launch_bounds__(448, 1)
void gru_attn_fused(const float* __restrict__ x,
                    const float* __restrict__ w_ih0, const float* __restrict__ w_hh0,
                    const float* __restrict__ b_ih0, const float* __restrict__ b_hh0,
                    const float* __restrict__ w_ih1, const float* __restrict__ w_hh1,
                    const float* __restrict__ b_ih1, const float* __restrict__ b_hh1,
                    const float* __restrict__ attn_w1, const float* __restrict__ attn_b1,
                    const float* __restrict__ attn_w2, const float* __restrict__ attn_b2,
                    const float* __restrict__ ln_g, const float* __restrict__ ln_b,
                    const float* __restrict__ head_w1, const float* __restrict__ head_b1,
                    const float* __restrict__ head_w2, const float* __restrict__ head_b2,
                    float* __restrict__ out)
{
  __shared__ float lds[LDSF];
  f16*   ldsx = (f16*)lds;
  float* xg0  = lds + XG0_B;
  float* xg1  = lds + XG1_B;
  f16*   h0h  = (f16*)(lds + H0H_B);
  f16*   h1h  = (f16*)(lds + H1H_B);
  float* h1f  = lds + H1F_B;

  const int tid  = threadIdx.x;
  const int wid  = tid >> 6;
  const int lane = tid & 63;
  const int b    = blockIdx.x;
  const float* xb = x + (size_t)b * 64 * TS;

  const int i2     = lane >> 1;
  const int p      = lane & 1;
  const int ownrow = i2 + 32*p;
  const int hoff   = p << 5;       // half offset (f16 elems)

  f16x2 W[96];       // role-overloaded weights (L: w_hh halves; F: w_ih; ATT: attn_w1)
  float4 SP[16];     // stage pipeline (wid4 only)
  float bA=0.f,bB=0.f,bC=0.f,w2o=0.f,b2v=0.f;

  if (wid < 4) {
    const float* wsrc = (wid==0)? w_hh0 : (wid==1)? w_hh1 : (wid==2)? w_ih1 : w_ih0;
    for (int r2=0;r2<2;r2++)
      for (int g=0;g<3;g++)
        for (int m=0;m<16;m++){
          const f32x2 v = *(const f32x2*)(wsrc + (size_t)(g*64 + i2 + 32*r2)*64 + hoff + 2*m);
          W[(r2*3+g)*16+m] = (f16x2){(f16)v.x,(f16)v.y};
        }
    for (int q2=0;q2<96;q2++) asm volatile("" : "+v"(W[q2]));
    const float* bsrc = (wid==0)? b_hh0 : (wid==1)? b_hh1 : (wid==2)? b_ih1 : b_ih0;
    bA = bsrc[ownrow]; bB = bsrc[64+ownrow]; bC = bsrc[128+ownrow];
  } else if (wid == 6) {
    for (int r2=0;r2<2;r2++)
      for (int m=0;m<16;m++){
        const f32x2 v = *(const f32x2*)(attn_w1 + (size_t)(i2+32*r2)*64 + hoff + 2*m);
        W[r2*16+m] = (f16x2){(f16)v.x,(f16)v.y};
      }
    for (int q2=0;q2<32;q2++) asm volatile("" : "+v"(W[q2]));
    bA = attn_b1[ownrow]; w2o = attn_w2[ownrow]; b2v = attn_b2[0];
  }

  // prologue: zero h rings; wid4 stages x tile 0 (lane=channel -> contiguous writes)
  for (int idx = tid; idx < 1024; idx += 448) ((uint32_t*)h0h)[idx] = 0u;
  for (int idx = tid; idx < 512;  idx += 448) ((uint32_t*)h1h)[idx] = 0u;
  if (wid == 4) {
    const float* src = xb + (size_t)lane*TS;
    #pragma unroll
    for (int kq=0;kq<16;kq++) SP[kq] = *(const float4*)(src + 4*kq);
    #pragma unroll
    for (int kq=0;kq<16;kq++){
      ldsx[(4*kq+0)*80 + lane] = (f16)SP[kq].x;
      ldsx[(4*kq+1)*80 + lane] = (f16)SP[kq].y;
      ldsx[(4*kq+2)*80 + lane] = (f16)SP[kq].z;
      ldsx[(4*kq+3)*80 + lane] = (f16)SP[kq].w;
    }
  }
  __syncthreads();

  if (wid <= 1) __builtin_amdgcn_s_setprio(1);

  float hreg = 0.f;                        // L-waves: own-row h master (f32)
  float am = -1e30f, aZ = 0.f, aP = 0.f;   // wid6 online softmax/pool

  #pragma unroll 1
  for (int k = -1; k <= 258; ++k) {
    if (wid <= 1) {
      // ---- recurrence: L0 @ block k, L1 @ block k-2 ----
      const int blk = k - (wid << 1);
      if (0 <= blk && blk < 256) {
        f16*   hring = wid ? h1h : h0h;
        float* xgc   = wid ? xg1 : xg0;
        const int emask = wid ? 1023 : 2047;   // ring elem mask (16 / 32 slots)
        #pragma unroll
        for (int j=0;j<8;j++){
          const int t  = (blk<<3) + j;
          const int xi = (t & 15) * 192;
          const float xgr = xgc[xi + ownrow];
          const float xgz = xgc[xi + 64 + ownrow];
          const float xgn = xgc[xi + 128 + ownrow];
          FEN();                                            // write(t-1) -> read(t)
          const f16* hv = hring + (((t-1)<<6) & emask) + hoff;
          float a00=0,a01=0,a02=0,a10=0,a11=0,a12=0;
          dot6(hv, W, a00,a01,a02,a10,a11,a12);
          a00=qadd1(a00); a01=qadd1(a01); a02=qadd1(a02);
          a10=qadd1(a10); a11=qadd1(a11); a12=qadd1(a12);
          const float hr = p ? a10 : a00;
          const float hz = p ? a11 : a01;
          const float hn = p ? a12 : a02;
          const float r = sigmoidf_(xgr + hr + bA);         // xg includes b_ih
          const float z = sigmoidf_(xgz + hz + bB);
          const float n = tanhf_(xgn + r*(hn + bC));
          hreg = n + z*(hreg - n);
          hring[((t<<6) & emask) + ownrow] = (f16)hreg;
          if (wid) h1f[((t&15)<<6) + ownrow] = hreg;
        }
      }
    } else if (wid <= 3) {
      // ---- feeders: F1 (xg1 from h0) @ k-1 ; F0 (xg0 from x) @ k+1 ----
      const int blk = (wid==2) ? k-1 : k+1;
      if (0 <= blk && blk < 256) {
        float* xgw = (wid==2) ? xg1 : xg0;
        #pragma unroll
        for (int j=0;j<8;j++){
          const int t = (blk<<3) + j;
          const f16* vec;
          if (wid==2) vec = h0h + (((t-1)<<6) & 2047) + hoff;
          else        vec = ldsx + ((t>>6)&1)*5120 + (t&63)*80 + hoff;
          float a00=0,a01=0,a02=0,a10=0,a11=0,a12=0;
          dot6(vec, W, a00,a01,a02,a10,a11,a12);
          a00=qadd1(a00); a01=qadd1(a01); a02=qadd1(a02);
          a10=qadd1(a10); a11=qadd1(a11); a12=qadd1(a12);
          const int xi = (t & 15) * 192;
          xgw[xi + ownrow]       = (p ? a10 : a00) + bA;
          xgw[xi + 64 + ownrow]  = (p ? a11 : a01) + bB;
          xgw[xi + 128 + ownrow] = (p ? a12 : a02) + bC;
        }
      }
    } else if (wid == 4) {
      // ---- x stager: tile m+1 loaded at phase 1, written at phase 5 ----
      const int kk = k + 1, tile = kk >> 3, ph = kk & 7;
      if (ph == 1 && tile < 31) {
        const float* src = xb + (size_t)lane*TS + (tile+1)*64;
        #pragma unroll
        for (int kq=0;kq<16;kq++) SP[kq] = *(const float4*)(src + 4*kq);
      } else if (ph == 5 && tile < 31) {
        f16* dsth = ldsx + ((tile+1)&1)*5120;
        #pragma unroll
        for (int kq=0;kq<16;kq++){
          dsth[(4*kq+0)*80 + lane] = (f16)SP[kq].x;
          dsth[(4*kq+1)*80 + lane] = (f16)SP[kq].y;
          dsth[(4*kq+2)*80 + lane] = (f16)SP[kq].z;
          dsth[(4*kq+3)*80 + lane] = (f16)SP[kq].w;
        }
      }
    } else if (wid == 6) {
      // ---- attention + online-softmax pooling @ block k-3 ----
      const int blk = k - 3;
      if (0 <= blk && blk < 256) {
        #pragma unroll
        for (int j=0;j<8;j++){
          const int t = (blk<<3) + j;
          const f16* hv = h1h + ((t&15)<<6) + hoff;
          H8 u[4];
          u[0].v8 = *(const f16x8*)(hv);
          u[1].v8 = *(const f16x8*)(hv+8);
          u[2].v8 = *(const f16x8*)(hv+16);
          u[3].v8 = *(const f16x8*)(hv+24);
          float a0=0.f, a1=0.f;
          #pragma unroll
          for (int m=0;m<16;m++){
            const f16x2 hm = u[m>>2].v2[m&3];
            a0 = fdot2_(W[m],    hm, a0);
            a1 = fdot2_(W[16+m], hm, a1);
          }
          a0 = qadd1(a0); a1 = qadd1(a1);
          const float a  = tanhf_((p ? a1 : a0) + bA);
          const float s  = wsum64(w2o * a) + b2v;
          const float hc = h1f[((t&15)<<6) + lane];
          const float mn = fmaxf(am, s);
          const float sc = __expf(am - mn);
          const float pp = __expf(s - mn);
          aZ = aZ*sc + pp;
          aP = aP*sc + pp*hc;
          am = mn;
        }
      }
    }
    BAR();
  }

  // ---------------- epilogue ----------------
  if (wid == 6) {
    const float pooled = aP / aZ;
    float mu = pooled;
    #pragma unroll
    for (int m=1;m<64;m<<=1) mu += __shfl_xor(mu, m, 64);
    mu *= (1.0f/64.0f);
    const float d = pooled - mu;
    float var = d*d;
    #pragma unroll
    for (int m=1;m<64;m<<=1) var += __shfl_xor(var, m, 64);
    var *= (1.0f/64.0f);
    const float y = d * rsqrtf(var + 1e-5f) * ln_g[lane] + ln_b[lane];
    lds[SCRO_B + lane] = y;
  }
  __syncthreads();
  if (tid < 32) {
    const float* hw = head_w1 + tid*64;
    float acc = head_b1[tid];
    #pragma unroll
    for (int kq=0;kq<16;kq++){
      const float4 w4 = ((const float4*)hw)[kq];
      acc += w4.x*lds[SCRO_B+4*kq+0] + w4.y*lds[SCRO_B+4*kq+1]
           + w4.z*lds[SCRO_B+4*kq+2] + w4.w*lds[SCRO_B+4*kq+3];
    }
    const float u = 0.5f*acc*(1.0f + erff(acc*0.70710678118654752f)); // exact GELU
    lds[SCRO_B + 64 + tid] = u;
  }
  __syncthreads();
  if (tid < 8) {
    const float* hw = head_w2 + tid*32;
    float acc = head_b2[tid];
    #pragma unroll
    for (int kq=0;kq<8;kq++){
      const float4 w4 = ((const float4*)hw)[kq];
      acc += w4.x*lds[SCRO_B+64+4*kq+0] + w4.y*lds[SCRO_B+64+4*kq+1]
           + w4.z*lds[SCRO_B+64+4*kq+2] + w4.w*lds[SCRO_B+64+4*kq+3];
    }
    out[b*8 + tid] = acc;
  }
}

extern "C" void kernel_launch(void* const* d_in, const int* in_sizes, int n_in,
                              void* d_out, int out_size, void* d_ws, size_t ws_size,
                              hipStream_t stream) {
  (void)in_sizes; (void)n_in; (void)d_ws; (void)ws_size; (void)out_size;
  const float* x       = (const float*)d_in[0];
  const float* w_ih0   = (const float*)d_in[1];
  const float* w_hh0   = (const float*)d_in[2];
  const float* b_ih0   = (const float*)d_in[3];
  const float* b_hh0   = (const float*)d_in[4];
  const float* w_ih1   = (const float*)d_in[5];
  const float* w_hh1   = (const float*)d_in[6];
  const float* b_ih1   = (const float*)d_in[7];
  const float* b_hh1   = (const float*)d_in[8];
  const float* attn_w1 = (const float*)d_in[9];
  const float* attn_b1 = (const float*)d_in[10];
  const float* attn_w2 = (const float*)d_in[11];
  const float* attn_b2 = (const float*)d_in[12];
  const float* ln_g    = (const float*)d_in[13];
  const float* ln_b    = (const float*)d_in[14];
  const float* head_w1 = (const float*)d_in[15];
  const float* head_b1 = (const float*)d_in[16];
  const float* head_w2 = (const float*)d_in[17];
  const float* head_b2 = (const float*)d_in[18];
  hipLaunchKernelGGL(gru_attn_fused, dim3(256), dim3(448), 0, stream,
                     x, w_ih0, w_hh0, b_ih0, b_hh0, w_ih1, w_hh1, b_ih1, b_hh1,
                     attn_w1, attn_b1, attn_w2, attn_b2, ln_g, ln_b,
                     head_w1, head_b1, head_w2, head_b2, (float*)d_out);
}